// Round 8
// baseline (253.884 us; speedup 1.0000x reference)
//
#include <hip/hip_runtime.h>
#include <hip/hip_bf16.h>
#include <stdint.h>

typedef __bf16 bf16x8 __attribute__((ext_vector_type(8)));
typedef __bf16 bf16x4 __attribute__((ext_vector_type(4)));
typedef float  f32x4  __attribute__((ext_vector_type(4)));

#define MFMA16(a, b, c) __builtin_amdgcn_mfma_f32_16x16x32_bf16(a, b, c, 0, 0, 0)

// async 16B global->LDS (dest = wave-uniform base + lane*16)
__device__ __forceinline__ void ld16(void* lds, const void* g) {
    __builtin_amdgcn_global_load_lds(
        (const __attribute__((address_space(1))) void*)(uintptr_t)g,
        (__attribute__((address_space(3))) void*)(uint32_t)(uintptr_t)lds,
        16, 0, 0);
}

// ---------------- f32 -> bf16 convert (x) -------------------------------------
__global__ __launch_bounds__(256) void convert_bf16(const float* __restrict__ src,
                                                    __bf16* __restrict__ dst) {
    int i = (blockIdx.x * 256 + threadIdx.x) * 4;
    float4 v = *(const float4*)(src + i);
    dst[i]     = (__bf16)v.x;
    dst[i + 1] = (__bf16)v.y;
    dst[i + 2] = (__bf16)v.z;
    dst[i + 3] = (__bf16)v.w;
}

// ---------------- weight transpose + cast: Wt[n][k] = (bf16)W[k][n] -----------
__global__ __launch_bounds__(1024) void transpose_w(const float* __restrict__ W0,
                                                    const float* __restrict__ W1,
                                                    const float* __restrict__ W2,
                                                    const float* __restrict__ W3,
                                                    __bf16* __restrict__ dst) {
    __shared__ __bf16 t[32][33];
    const int z = blockIdx.z;
    const float* W = (z == 0) ? W0 : (z == 1) ? W1 : (z == 2) ? W2 : W3;
    __bf16* D = dst + (size_t)z * 1048576;
    const int tx = threadIdx.x, ty = threadIdx.y;
    t[ty][tx] = (__bf16)W[(size_t)(blockIdx.y * 32 + ty) * 1024 + blockIdx.x * 32 + tx];
    __syncthreads();
    D[(size_t)(blockIdx.x * 32 + ty) * 1024 + blockIdx.y * 32 + tx] = t[tx][ty];
}

// ---------------- shared GEMM mainloop: C[128x128] += A[128xK] * BT[128xK]^T ----
__device__ __forceinline__ void gemm_mainloop(const __bf16* __restrict__ A,
                                              const __bf16* __restrict__ BT,
                                              int K, __bf16* As, __bf16* Bs,
                                              f32x4 acc[4][4]) {
    const int tid  = threadIdx.x;
    const int lane = tid & 63;
    const int wid  = tid >> 6;
    const int quad = lane >> 4;
    const int l16  = lane & 15;
    const int wm   = wid >> 1;
    const int wn   = wid & 1;

    const int srow = wid * 16 + (lane >> 2);
    const int scol = (lane & 3) * 8;
    const int sdst = wid * 512 + lane * 8;

    for (int k0 = 0; k0 < K; k0 += 32) {
        ld16(As + sdst,        A  + (size_t)srow        * K + k0 + scol);
        ld16(As + 2048 + sdst, A  + (size_t)(srow + 64) * K + k0 + scol);
        ld16(Bs + sdst,        BT + (size_t)srow        * K + k0 + scol);
        ld16(Bs + 2048 + sdst, BT + (size_t)(srow + 64) * K + k0 + scol);
        __syncthreads();
        bf16x8 af[4], bf[4];
#pragma unroll
        for (int mt = 0; mt < 4; mt++)
            af[mt] = *(const bf16x8*)(As + (wm * 64 + mt * 16 + l16) * 32 + quad * 8);
#pragma unroll
        for (int nt = 0; nt < 4; nt++)
            bf[nt] = *(const bf16x8*)(Bs + (wn * 64 + nt * 16 + l16) * 32 + quad * 8);
#pragma unroll
        for (int mt = 0; mt < 4; mt++)
#pragma unroll
            for (int nt = 0; nt < 4; nt++)
                acc[mt][nt] = MFMA16(af[mt], bf[nt], acc[mt][nt]);
        __syncthreads();
    }
}

// ---------------- QKV projection: X @ W{q,k,v} + b ------------------------------
// z=0 -> Q [B,H,T,HD] PRE-SCALED by (1/8)*log2(e), z=1 -> K, z=2 -> V^T [B,H,HD,T]
__global__ __launch_bounds__(256) void qkv_gemm(const __bf16* __restrict__ X,
                                                const __bf16* __restrict__ WTb,
                                                const float* __restrict__ b0,
                                                const float* __restrict__ b1,
                                                const float* __restrict__ b2,
                                                __bf16* __restrict__ qk,
                                                __bf16* __restrict__ vt) {
    __shared__ __attribute__((aligned(16))) __bf16 As[4096];
    __shared__ __attribute__((aligned(16))) __bf16 Bs[4096];
    const int z = blockIdx.z;
    const __bf16* BT   = WTb + (size_t)z * 1048576;
    const float* bias  = (z == 0) ? b0 : (z == 1) ? b1 : b2;
    const int m0 = blockIdx.y * 128, n0 = blockIdx.x * 128;
    f32x4 acc[4][4];
    const f32x4 zz = {0.f, 0.f, 0.f, 0.f};
#pragma unroll
    for (int i = 0; i < 4; i++)
#pragma unroll
        for (int j = 0; j < 4; j++) acc[i][j] = zz;
    gemm_mainloop(X + (size_t)m0 * 1024, BT + (size_t)n0 * 1024, 1024, As, Bs, acc);

    const int lane = threadIdx.x & 63, wid = threadIdx.x >> 6;
    const int quad = lane >> 4, l16 = lane & 15, wm = wid >> 1, wn = wid & 1;
    if (z == 2) {
        // V^T epilogue: vt[((b*16+h)*64+hd)*2048 + t], 4 consecutive t packed
#pragma unroll
        for (int nt = 0; nt < 4; nt++) {
            int col = n0 + wn * 64 + nt * 16 + l16;
            float bv = bias[col];
            int h = col >> 6, hd = col & 63;
#pragma unroll
            for (int mt = 0; mt < 4; mt++) {
                int m = m0 + wm * 64 + mt * 16 + quad * 4;
                int b = m >> 11, tt = m & 2047;
                bf16x4 pk;
                pk.x = (__bf16)(acc[mt][nt].x + bv);
                pk.y = (__bf16)(acc[mt][nt].y + bv);
                pk.z = (__bf16)(acc[mt][nt].z + bv);
                pk.w = (__bf16)(acc[mt][nt].w + bv);
                *(bf16x4*)(vt + ((size_t)((b * 16 + h) * 64 + hd)) * 2048 + tt) = pk;
            }
        }
    } else {
        // softmax scale (1/sqrt(64))*log2(e) folded into Q here (z==0)
        const float sq = (z == 0) ? 0.18033688011112042f : 1.0f;
        __bf16* dst = qk + (size_t)z * 4194304;
#pragma unroll
        for (int nt = 0; nt < 4; nt++) {
            int col = n0 + wn * 64 + nt * 16 + l16;
            float bv = bias[col];
            int h = col >> 6, hd = col & 63;
#pragma unroll
            for (int mt = 0; mt < 4; mt++) {
#pragma unroll
                for (int r4 = 0; r4 < 4; r4++) {
                    int m = m0 + wm * 64 + mt * 16 + quad * 4 + r4;
                    int b = m >> 11, tt = m & 2047;
                    float v = (acc[mt][nt][r4] + bv) * sq;
                    dst[((size_t)((b * 16 + h) * 2048 + tt)) * 64 + hd] = (__bf16)v;
                }
            }
        }
    }
}

// ---------------- output projection: Y @ Wp + bp -> out [B,T,C] f32 ------------
__global__ __launch_bounds__(256) void proj_gemm(const __bf16* __restrict__ Yw,
                                                 const __bf16* __restrict__ WT,
                                                 const float* __restrict__ bias,
                                                 float* __restrict__ out) {
    __shared__ __attribute__((aligned(16))) __bf16 As[4096];
    __shared__ __attribute__((aligned(16))) __bf16 Bs[4096];
    const int m0 = blockIdx.y * 128, n0 = blockIdx.x * 128;
    f32x4 acc[4][4];
    const f32x4 zz = {0.f, 0.f, 0.f, 0.f};
#pragma unroll
    for (int i = 0; i < 4; i++)
#pragma unroll
        for (int j = 0; j < 4; j++) acc[i][j] = zz;
    gemm_mainloop(Yw + (size_t)m0 * 1024, WT + (size_t)n0 * 1024, 1024, As, Bs, acc);

    const int lane = threadIdx.x & 63, wid = threadIdx.x >> 6;
    const int quad = lane >> 4, l16 = lane & 15, wm = wid >> 1, wn = wid & 1;
#pragma unroll
    for (int nt = 0; nt < 4; nt++) {
        int col = n0 + wn * 64 + nt * 16 + l16;
        float bv = bias[col];
#pragma unroll
        for (int mt = 0; mt < 4; mt++) {
#pragma unroll
            for (int r4 = 0; r4 < 4; r4++) {
                int m = m0 + wm * 64 + mt * 16 + quad * 4 + r4;
                out[(size_t)m * 1024 + col] = acc[mt][nt][r4] + bv;
            }
        }
    }
}

// ---------------- flash attention v6 -------------------------------------------
// v5 + XCD-aware block remap: with the observed round-robin dispatch
// (XCD = blockIdx.x % 8), bh = (p&7)*4 + ((p>>3)&3) pins each XCD to 4 heads
// -> per-XCD K+V working set 2 MB < 4 MB L2 (was 16 MB spanning all 32 heads,
// forcing ~557 MB of K/V fragment re-reads to L3 at ~6.3 TB/s = the R7 wall).
// Pure locality heuristic: any (bx,bh) is computed exactly once regardless of
// the real dispatch mapping. Everything else identical to v5.
__global__ __launch_bounds__(256, 3) void attn_kernel(const __bf16* __restrict__ Qg,
                                                      const __bf16* __restrict__ Kg,
                                                      const __bf16* __restrict__ Vtg,
                                                      __bf16* __restrict__ Y) {
    __shared__ __attribute__((aligned(16))) __bf16 Ps[4][32 * 136];
    __shared__ __attribute__((aligned(16))) float  Lw[4][32];   // per-wave l
    __shared__ __attribute__((aligned(16))) float  Linv[32];    // 1/l merged

    const int tid  = threadIdx.x;
    const int lane = tid & 63;
    const int wid  = tid >> 6;
    const int quad = lane >> 4;
    const int l16  = lane & 15;
    const int p    = blockIdx.x;
    const int bh       = (p & 7) * 4 + ((p >> 3) & 3);  // XCD-pinned head
    const int pairidx  = p >> 5;                        // 0..31
    const f32x4 zz = {0.f, 0.f, 0.f, 0.f};

#pragma unroll 1
    for (int itm = 0; itm < 2; itm++) {
        const int bx  = itm ? (63 - pairidx) : pairidx;
        const int q0  = bx * 32;
        const int ktlast = bx >> 2;
        const bool halfdiag = (bx & 3) < 2;   // diag tile: keys 64-127 all masked
        const size_t hbase = (size_t)bh * (2048 * 64);

        // Q fragments (B-layout, pre-scaled) for the item's 32 q rows
        bf16x8 qf[2][2];
#pragma unroll
        for (int nt = 0; nt < 2; nt++)
#pragma unroll
            for (int kk = 0; kk < 2; kk++)
                qf[nt][kk] = *(const bf16x8*)(Qg + hbase +
                                              (size_t)(q0 + nt * 16 + l16) * 64 +
                                              kk * 32 + quad * 8);

        f32x4 acc_o[2][4];
#pragma unroll
        for (int i = 0; i < 2; i++)
#pragma unroll
            for (int j = 0; j < 4; j++) acc_o[i][j] = zz;
        float l_s[2] = {0.f, 0.f};

        for (int kt = wid; kt <= ktlast; kt += 4) {
            const int key0 = kt << 7;
            const bool diag = (kt == ktlast);
            const bool skipB = diag && halfdiag;
            float s_s[2] = {0.f, 0.f};

            // ======== HALF A: keys key0+[0,64) (mt 0..3) ========
            {
                f32x4 accs[4][2];
#pragma unroll
                for (int mt = 0; mt < 4; mt++) { accs[mt][0] = zz; accs[mt][1] = zz; }
#pragma unroll
                for (int kk = 0; kk < 2; kk++) {
#pragma unroll
                    for (int mt = 0; mt < 4; mt++) {
                        bf16x8 kf = *(const bf16x8*)(Kg + hbase +
                                                     (size_t)(key0 + mt * 16 + l16) * 64 +
                                                     kk * 32 + quad * 8);
                        accs[mt][0] = MFMA16(kf, qf[0][kk], accs[mt][0]);
                        accs[mt][1] = MFMA16(kf, qf[1][kk], accs[mt][1]);
                    }
                }
                if (diag) {
#pragma unroll
                    for (int mt = 0; mt < 4; mt++)
#pragma unroll
                        for (int nt = 0; nt < 2; nt++) {
                            int q_g = q0 + nt * 16 + l16;
#pragma unroll
                            for (int r4 = 0; r4 < 4; r4++) {
                                int key_g = key0 + mt * 16 + quad * 4 + r4;
                                if (key_g > q_g) accs[mt][nt][r4] = -1e30f;
                            }
                        }
                }
#pragma unroll
                for (int mt = 0; mt < 4; mt++)
#pragma unroll
                    for (int nt = 0; nt < 2; nt++) {
                        f32x4 pv;
                        pv.x = exp2f(accs[mt][nt].x);
                        pv.y = exp2f(accs[mt][nt].y);
                        pv.z = exp2f(accs[mt][nt].z);
                        pv.w = exp2f(accs[mt][nt].w);
                        s_s[nt] += (pv.x + pv.y) + (pv.z + pv.w);
                        bf16x4 pk;
                        pk.x = (__bf16)pv.x; pk.y = (__bf16)pv.y;
                        pk.z = (__bf16)pv.z; pk.w = (__bf16)pv.w;
                        *(bf16x4*)(&Ps[wid][(nt * 16 + l16) * 136 +
                                            mt * 16 + quad * 4]) = pk;
                    }
            }

            // ======== HALF B: keys key0+[64,128) (mt 4..7), skipped if fully masked
            if (!skipB) {
                f32x4 accs[4][2];
#pragma unroll
                for (int mt = 0; mt < 4; mt++) { accs[mt][0] = zz; accs[mt][1] = zz; }
#pragma unroll
                for (int kk = 0; kk < 2; kk++) {
#pragma unroll
                    for (int mt = 0; mt < 4; mt++) {
                        bf16x8 kf = *(const bf16x8*)(Kg + hbase +
                                                     (size_t)(key0 + 64 + mt * 16 + l16) * 64 +
                                                     kk * 32 + quad * 8);
                        accs[mt][0] = MFMA16(kf, qf[0][kk], accs[mt][0]);
                        accs[mt][1] = MFMA16(kf, qf[1][kk], accs[mt][1]);
                    }
                }
                if (diag) {
#pragma unroll
                    for (int mt = 0; mt < 4; mt++)
#pragma unroll
                        for (int nt = 0; nt < 2; nt++) {
                            int q_g = q0 + nt * 16 + l16;
#pragma unroll
                            for (int r4 = 0; r4 < 4; r4++) {
                                int key_g = key0 + 64 + mt * 16 + quad * 4 + r4;
                                if (key_g > q_g) accs[mt][nt][r4] = -1e30f;
                            }
                        }
                }
#pragma unroll
                for (int mt = 0; mt < 4; mt++)
#pragma unroll
                    for (int nt = 0; nt < 2; nt++) {
                        f32x4 pv;
                        pv.x = exp2f(accs[mt][nt].x);
                        pv.y = exp2f(accs[mt][nt].y);
                        pv.z = exp2f(accs[mt][nt].z);
                        pv.w = exp2f(accs[mt][nt].w);
                        s_s[nt] += (pv.x + pv.y) + (pv.z + pv.w);
                        bf16x4 pk;
                        pk.x = (__bf16)pv.x; pk.y = (__bf16)pv.y;
                        pk.z = (__bf16)pv.z; pk.w = (__bf16)pv.w;
                        *(bf16x4*)(&Ps[wid][(nt * 16 + l16) * 136 +
                                            64 + mt * 16 + quad * 4]) = pk;
                    }
            }

#pragma unroll
            for (int nt = 0; nt < 2; nt++) {
                float t = s_s[nt];
                t += __shfl_xor(t, 16);
                t += __shfl_xor(t, 32);
                l_s[nt] += t;
            }

            // ---- O += P * V (A=P from own-wave LDS b128, B=V^T direct global) ----
#pragma unroll
            for (int kk = 0; kk < 2; kk++) {
                bf16x8 pf[2], vf[4];
#pragma unroll
                for (int mtP = 0; mtP < 2; mtP++)
                    pf[mtP] = *(const bf16x8*)(&Ps[wid][(mtP * 16 + l16) * 136 +
                                                        kk * 32 + quad * 8]);
#pragma unroll
                for (int nv = 0; nv < 4; nv++)
                    vf[nv] = *(const bf16x8*)(Vtg + hbase +
                                              (size_t)(nv * 16 + l16) * 2048 +
                                              key0 + kk * 32 + quad * 8);
#pragma unroll
                for (int mtP = 0; mtP < 2; mtP++)
#pragma unroll
                    for (int nv = 0; nv < 4; nv++)
                        acc_o[mtP][nv] = MFMA16(pf[mtP], vf[nv], acc_o[mtP][nv]);
            }
            if (!skipB) {
#pragma unroll
                for (int kk = 2; kk < 4; kk++) {
                    bf16x8 pf[2], vf[4];
#pragma unroll
                    for (int mtP = 0; mtP < 2; mtP++)
                        pf[mtP] = *(const bf16x8*)(&Ps[wid][(mtP * 16 + l16) * 136 +
                                                            kk * 32 + quad * 8]);
#pragma unroll
                    for (int nv = 0; nv < 4; nv++)
                        vf[nv] = *(const bf16x8*)(Vtg + hbase +
                                                  (size_t)(nv * 16 + l16) * 2048 +
                                                  key0 + kk * 32 + quad * 8);
#pragma unroll
                    for (int mtP = 0; mtP < 2; mtP++)
#pragma unroll
                        for (int nv = 0; nv < 4; nv++)
                            acc_o[mtP][nv] = MFMA16(pf[mtP], vf[nv], acc_o[mtP][nv]);
                }
            }
        }

        // ================= merge of 4 key-split partials (sum only) =============
        if (quad == 0) { Lw[wid][l16] = l_s[0]; Lw[wid][16 + l16] = l_s[1]; }
        __syncthreads();
        if (wid == 0 && quad == 0) {
#pragma unroll
            for (int nt = 0; nt < 2; nt++) {
                int qq = nt * 16 + l16;
                Linv[qq] = 1.0f / (Lw[0][qq] + Lw[1][qq] + Lw[2][qq] + Lw[3][qq]);
            }
        }
        // own-wave slice of Ps reused as f32 partial: Om[32 rows][68 stride]
        float* Om = (float*)&Ps[0][0];
#pragma unroll
        for (int mtP = 0; mtP < 2; mtP++)
#pragma unroll
            for (int nv = 0; nv < 4; nv++)
#pragma unroll
                for (int r4 = 0; r4 < 4; r4++)
                    Om[wid * 2176 + (mtP * 16 + quad * 4 + r4) * 68 + nv * 16 + l16] =
                        acc_o[mtP][nv][r4];
        __syncthreads();

        // sum 4 partials, scale by 1/l, write Y (16B coalesced)
        {
            const int q  = tid >> 3;          // 0..31
            const int c0 = (tid & 7) * 8;     // 0..56
            f32x4 s0 = zz, s1 = zz;
#pragma unroll
            for (int w = 0; w < 4; w++) {
                s0 += *(const f32x4*)(&Om[w * 2176 + q * 68 + c0]);
                s1 += *(const f32x4*)(&Om[w * 2176 + q * 68 + c0 + 4]);
            }
            float li = Linv[q];
            bf16x8 o;
            o[0] = (__bf16)(s0.x * li); o[1] = (__bf16)(s0.y * li);
            o[2] = (__bf16)(s0.z * li); o[3] = (__bf16)(s0.w * li);
            o[4] = (__bf16)(s1.x * li); o[5] = (__bf16)(s1.y * li);
            o[6] = (__bf16)(s1.z * li); o[7] = (__bf16)(s1.w * li);
            const int b = bh >> 4, h = bh & 15;
            *(bf16x8*)(Y + ((size_t)(b * 2048 + q0 + q)) * 1024 + h * 64 + c0) = o;
        }
        __syncthreads();   // protect Ps/Lw reuse by the next item
    }
}

// ws layout (bf16 elems), 40 MB total:
// [0,4Mi)     x as bf16 (dead after qkv) -> reused as Y [B,T,C]
// [4Mi,8Mi)   W^T x4 (Wq,Wk,Wv,Wp)
// [8Mi,12Mi)  Q [B,H,T,HD] (pre-scaled)
// [12Mi,16Mi) K [B,H,T,HD]
// [16Mi,20Mi) V^T [B,H,HD,T]  (written directly by qkv_gemm z=2)
#define XB_OFF  0
#define WT_OFF  4194304
#define Q_OFF   8388608
#define K_OFF   12582912
#define VT_OFF  16777216
#define Y_OFF   0

extern "C" void kernel_launch(void* const* d_in, const int* in_sizes, int n_in,
                              void* d_out, int out_size, void* d_ws, size_t ws_size,
                              hipStream_t stream) {
    const float* x  = (const float*)d_in[0];
    const float* Wq = (const float*)d_in[1];
    const float* bq = (const float*)d_in[2];
    const float* Wk = (const float*)d_in[3];
    const float* bk = (const float*)d_in[4];
    const float* Wv = (const float*)d_in[5];
    const float* bv = (const float*)d_in[6];
    const float* Wp = (const float*)d_in[7];
    const float* bp = (const float*)d_in[8];
    __bf16* ws  = (__bf16*)d_ws;
    float*  out = (float*)d_out;
    if (ws_size < (size_t)41943040) return;  // need 40 MB scratch

    convert_bf16<<<4096, 256, 0, stream>>>(x, ws + XB_OFF);
    transpose_w<<<dim3(32, 32, 4), dim3(32, 32), 0, stream>>>(Wq, Wk, Wv, Wp, ws + WT_OFF);
    qkv_gemm<<<dim3(8, 32, 3), 256, 0, stream>>>(ws + XB_OFF, ws + WT_OFF, bq, bk, bv,
                                                 ws + Q_OFF, ws + VT_OFF);
    attn_kernel<<<dim3(1024), 256, 0, stream>>>(ws + Q_OFF, ws + K_OFF, ws + VT_OFF,
                                                ws + Y_OFF);
    proj_gemm<<<dim3(8, 32), 256, 0, stream>>>(ws + Y_OFF, ws + WT_OFF + 3 * 1048576, bp, out);
}

// Round 9
// 253.070 us; speedup vs baseline: 1.0032x; 1.0032x over previous
//
#include <hip/hip_runtime.h>
#include <hip/hip_bf16.h>
#include <stdint.h>

typedef __bf16 bf16x8 __attribute__((ext_vector_type(8)));
typedef __bf16 bf16x4 __attribute__((ext_vector_type(4)));
typedef float  f32x4  __attribute__((ext_vector_type(4)));

#define MFMA16(a, b, c) __builtin_amdgcn_mfma_f32_16x16x32_bf16(a, b, c, 0, 0, 0)

// async 16B global->LDS (dest = wave-uniform base + lane*16)
__device__ __forceinline__ void ld16(void* lds, const void* g) {
    __builtin_amdgcn_global_load_lds(
        (const __attribute__((address_space(1))) void*)(uintptr_t)g,
        (__attribute__((address_space(3))) void*)(uint32_t)(uintptr_t)lds,
        16, 0, 0);
}

// ---------------- f32 -> bf16 convert (x) -------------------------------------
__global__ __launch_bounds__(256) void convert_bf16(const float* __restrict__ src,
                                                    __bf16* __restrict__ dst) {
    int i = (blockIdx.x * 256 + threadIdx.x) * 4;
    float4 v = *(const float4*)(src + i);
    dst[i]     = (__bf16)v.x;
    dst[i + 1] = (__bf16)v.y;
    dst[i + 2] = (__bf16)v.z;
    dst[i + 3] = (__bf16)v.w;
}

// ---------------- weight transpose + cast: Wt[n][k] = (bf16)W[k][n] -----------
__global__ __launch_bounds__(1024) void transpose_w(const float* __restrict__ W0,
                                                    const float* __restrict__ W1,
                                                    const float* __restrict__ W2,
                                                    const float* __restrict__ W3,
                                                    __bf16* __restrict__ dst) {
    __shared__ __bf16 t[32][33];
    const int z = blockIdx.z;
    const float* W = (z == 0) ? W0 : (z == 1) ? W1 : (z == 2) ? W2 : W3;
    __bf16* D = dst + (size_t)z * 1048576;
    const int tx = threadIdx.x, ty = threadIdx.y;
    t[ty][tx] = (__bf16)W[(size_t)(blockIdx.y * 32 + ty) * 1024 + blockIdx.x * 32 + tx];
    __syncthreads();
    D[(size_t)(blockIdx.x * 32 + ty) * 1024 + blockIdx.y * 32 + tx] = t[tx][ty];
}

// ---------------- shared GEMM mainloop: C[128x128] += A[128xK] * BT[128xK]^T ----
__device__ __forceinline__ void gemm_mainloop(const __bf16* __restrict__ A,
                                              const __bf16* __restrict__ BT,
                                              int K, __bf16* As, __bf16* Bs,
                                              f32x4 acc[4][4]) {
    const int tid  = threadIdx.x;
    const int lane = tid & 63;
    const int wid  = tid >> 6;
    const int quad = lane >> 4;
    const int l16  = lane & 15;
    const int wm   = wid >> 1;
    const int wn   = wid & 1;

    const int srow = wid * 16 + (lane >> 2);
    const int scol = (lane & 3) * 8;
    const int sdst = wid * 512 + lane * 8;

    for (int k0 = 0; k0 < K; k0 += 32) {
        ld16(As + sdst,        A  + (size_t)srow        * K + k0 + scol);
        ld16(As + 2048 + sdst, A  + (size_t)(srow + 64) * K + k0 + scol);
        ld16(Bs + sdst,        BT + (size_t)srow        * K + k0 + scol);
        ld16(Bs + 2048 + sdst, BT + (size_t)(srow + 64) * K + k0 + scol);
        __syncthreads();
        bf16x8 af[4], bf[4];
#pragma unroll
        for (int mt = 0; mt < 4; mt++)
            af[mt] = *(const bf16x8*)(As + (wm * 64 + mt * 16 + l16) * 32 + quad * 8);
#pragma unroll
        for (int nt = 0; nt < 4; nt++)
            bf[nt] = *(const bf16x8*)(Bs + (wn * 64 + nt * 16 + l16) * 32 + quad * 8);
#pragma unroll
        for (int mt = 0; mt < 4; mt++)
#pragma unroll
            for (int nt = 0; nt < 4; nt++)
                acc[mt][nt] = MFMA16(af[mt], bf[nt], acc[mt][nt]);
        __syncthreads();
    }
}

// ---------------- QKV projection: X @ W{q,k,v} + b ------------------------------
// z=0 -> Q [B,H,T,HD] PRE-SCALED by (1/8)*log2(e), z=1 -> K [B,H,T,HD],
// z=2 -> V^T TILED: [BH][T/128][HD=64][128]  (hd-row stride 256 B, tile 16 KB
//        contiguous -- avoids the 4 KB stride L2-channel collision of R8)
__global__ __launch_bounds__(256) void qkv_gemm(const __bf16* __restrict__ X,
                                                const __bf16* __restrict__ WTb,
                                                const float* __restrict__ b0,
                                                const float* __restrict__ b1,
                                                const float* __restrict__ b2,
                                                __bf16* __restrict__ qk,
                                                __bf16* __restrict__ vt) {
    __shared__ __attribute__((aligned(16))) __bf16 As[4096];
    __shared__ __attribute__((aligned(16))) __bf16 Bs[4096];
    const int z = blockIdx.z;
    const __bf16* BT   = WTb + (size_t)z * 1048576;
    const float* bias  = (z == 0) ? b0 : (z == 1) ? b1 : b2;
    const int m0 = blockIdx.y * 128, n0 = blockIdx.x * 128;
    f32x4 acc[4][4];
    const f32x4 zz = {0.f, 0.f, 0.f, 0.f};
#pragma unroll
    for (int i = 0; i < 4; i++)
#pragma unroll
        for (int j = 0; j < 4; j++) acc[i][j] = zz;
    gemm_mainloop(X + (size_t)m0 * 1024, BT + (size_t)n0 * 1024, 1024, As, Bs, acc);

    const int lane = threadIdx.x & 63, wid = threadIdx.x >> 6;
    const int quad = lane >> 4, l16 = lane & 15, wm = wid >> 1, wn = wid & 1;
    if (z == 2) {
#pragma unroll
        for (int nt = 0; nt < 4; nt++) {
            int col = n0 + wn * 64 + nt * 16 + l16;
            float bv = bias[col];
            int h = col >> 6, hd = col & 63;
#pragma unroll
            for (int mt = 0; mt < 4; mt++) {
                int m = m0 + wm * 64 + mt * 16 + quad * 4;
                int b = m >> 11, tt = m & 2047;
                int ttile = tt >> 7, toff = tt & 127;
                bf16x4 pk;
                pk.x = (__bf16)(acc[mt][nt].x + bv);
                pk.y = (__bf16)(acc[mt][nt].y + bv);
                pk.z = (__bf16)(acc[mt][nt].z + bv);
                pk.w = (__bf16)(acc[mt][nt].w + bv);
                *(bf16x4*)(vt + (((size_t)(b * 16 + h) * 16 + ttile) * 64 + hd) * 128 +
                           toff) = pk;
            }
        }
    } else {
        // softmax scale (1/sqrt(64))*log2(e) folded into Q here (z==0)
        const float sq = (z == 0) ? 0.18033688011112042f : 1.0f;
        __bf16* dst = qk + (size_t)z * 4194304;
#pragma unroll
        for (int nt = 0; nt < 4; nt++) {
            int col = n0 + wn * 64 + nt * 16 + l16;
            float bv = bias[col];
            int h = col >> 6, hd = col & 63;
#pragma unroll
            for (int mt = 0; mt < 4; mt++) {
#pragma unroll
                for (int r4 = 0; r4 < 4; r4++) {
                    int m = m0 + wm * 64 + mt * 16 + quad * 4 + r4;
                    int b = m >> 11, tt = m & 2047;
                    float v = (acc[mt][nt][r4] + bv) * sq;
                    dst[((size_t)((b * 16 + h) * 2048 + tt)) * 64 + hd] = (__bf16)v;
                }
            }
        }
    }
}

// ---------------- output projection: Y @ Wp + bp -> out [B,T,C] f32 ------------
__global__ __launch_bounds__(256) void proj_gemm(const __bf16* __restrict__ Yw,
                                                 const __bf16* __restrict__ WT,
                                                 const float* __restrict__ bias,
                                                 float* __restrict__ out) {
    __shared__ __attribute__((aligned(16))) __bf16 As[4096];
    __shared__ __attribute__((aligned(16))) __bf16 Bs[4096];
    const int m0 = blockIdx.y * 128, n0 = blockIdx.x * 128;
    f32x4 acc[4][4];
    const f32x4 zz = {0.f, 0.f, 0.f, 0.f};
#pragma unroll
    for (int i = 0; i < 4; i++)
#pragma unroll
        for (int j = 0; j < 4; j++) acc[i][j] = zz;
    gemm_mainloop(Yw + (size_t)m0 * 1024, WT + (size_t)n0 * 1024, 1024, As, Bs, acc);

    const int lane = threadIdx.x & 63, wid = threadIdx.x >> 6;
    const int quad = lane >> 4, l16 = lane & 15, wm = wid >> 1, wn = wid & 1;
#pragma unroll
    for (int nt = 0; nt < 4; nt++) {
        int col = n0 + wn * 64 + nt * 16 + l16;
        float bv = bias[col];
#pragma unroll
        for (int mt = 0; mt < 4; mt++) {
#pragma unroll
            for (int r4 = 0; r4 < 4; r4++) {
                int m = m0 + wm * 64 + mt * 16 + quad * 4 + r4;
                out[(size_t)m * 1024 + col] = acc[mt][nt][r4] + bv;
            }
        }
    }
}

// ---------------- flash attention v7 -------------------------------------------
// v6 + (a) tiled V^T layout (16 KB contiguous per 128-key tile; hd-row stride
// 256 B -- kills the 4 KB-stride L2 channel collision that was the ~12k-cyc/
// tile wall across v2b..v6), (b) K/V loads hoisted into arrays so 8 loads are
// in flight per s_waitcnt instead of load->wait->use serialization,
// (c) __launch_bounds__(256,2) so the allocator has room for the batches.
// Per-half P slot (stride 72, 144 B rows -> 16 B-aligned b128 reads).
__global__ __launch_bounds__(256, 2) void attn_kernel(const __bf16* __restrict__ Qg,
                                                      const __bf16* __restrict__ Kg,
                                                      const __bf16* __restrict__ Vtg,
                                                      __bf16* __restrict__ Y) {
    // per-wave 9216-B slot: P half-tile (32 rows x 72 bf16) during the loop,
    // f32 merge partial (32 rows x 72 f32) afterwards.
    __shared__ __attribute__((aligned(16))) unsigned char smem[4 * 9216];
    __shared__ __attribute__((aligned(16))) float Lw[4][32];   // per-wave l
    __shared__ __attribute__((aligned(16))) float Linv[32];    // 1/l merged

    const int tid  = threadIdx.x;
    const int lane = tid & 63;
    const int wid  = tid >> 6;
    const int quad = lane >> 4;
    const int l16  = lane & 15;
    const int p    = blockIdx.x;
    const int bh      = (p & 7) * 4 + ((p >> 3) & 3);  // XCD-pinned head
    const int pairidx = p >> 5;                        // 0..31
    const f32x4 zz = {0.f, 0.f, 0.f, 0.f};

    __bf16* Psw = (__bf16*)(smem + wid * 9216);

#pragma unroll 1
    for (int itm = 0; itm < 2; itm++) {
        const int bx  = itm ? (63 - pairidx) : pairidx;
        const int q0  = bx * 32;
        const int ktlast = bx >> 2;
        const bool halfdiag = (bx & 3) < 2;   // diag tile: keys 64-127 all masked
        const size_t hbase = (size_t)bh * (2048 * 64);

        // Q fragments (B-layout, pre-scaled) for the item's 32 q rows
        bf16x8 qf[2][2];
#pragma unroll
        for (int nt = 0; nt < 2; nt++)
#pragma unroll
            for (int kk = 0; kk < 2; kk++)
                qf[nt][kk] = *(const bf16x8*)(Qg + hbase +
                                              (size_t)(q0 + nt * 16 + l16) * 64 +
                                              kk * 32 + quad * 8);

        f32x4 acc_o[2][4];
#pragma unroll
        for (int i = 0; i < 2; i++)
#pragma unroll
            for (int j = 0; j < 4; j++) acc_o[i][j] = zz;
        float l_s[2] = {0.f, 0.f};

        for (int kt = wid; kt <= ktlast; kt += 4) {
            const int key0 = kt << 7;
            const bool diag = (kt == ktlast);
            const bool skipB = diag && halfdiag;
            const size_t vtbase = ((size_t)bh * 16 + kt) * 8192;  // tiled V^T
            float s_s[2] = {0.f, 0.f};

            // ======== HALF A: keys key0+[0,64) ========
            {
                bf16x8 kf[2][4];
#pragma unroll
                for (int kk = 0; kk < 2; kk++)
#pragma unroll
                    for (int mt = 0; mt < 4; mt++)
                        kf[kk][mt] = *(const bf16x8*)(Kg + hbase +
                                      (size_t)(key0 + mt * 16 + l16) * 64 +
                                      kk * 32 + quad * 8);
                f32x4 accs[4][2];
#pragma unroll
                for (int mt = 0; mt < 4; mt++) { accs[mt][0] = zz; accs[mt][1] = zz; }
#pragma unroll
                for (int kk = 0; kk < 2; kk++)
#pragma unroll
                    for (int mt = 0; mt < 4; mt++) {
                        accs[mt][0] = MFMA16(kf[kk][mt], qf[0][kk], accs[mt][0]);
                        accs[mt][1] = MFMA16(kf[kk][mt], qf[1][kk], accs[mt][1]);
                    }
                if (diag) {
#pragma unroll
                    for (int mt = 0; mt < 4; mt++)
#pragma unroll
                        for (int nt = 0; nt < 2; nt++) {
                            int q_g = q0 + nt * 16 + l16;
#pragma unroll
                            for (int r4 = 0; r4 < 4; r4++) {
                                int key_g = key0 + mt * 16 + quad * 4 + r4;
                                if (key_g > q_g) accs[mt][nt][r4] = -1e30f;
                            }
                        }
                }
#pragma unroll
                for (int mt = 0; mt < 4; mt++)
#pragma unroll
                    for (int nt = 0; nt < 2; nt++) {
                        f32x4 pv;
                        pv.x = exp2f(accs[mt][nt].x);
                        pv.y = exp2f(accs[mt][nt].y);
                        pv.z = exp2f(accs[mt][nt].z);
                        pv.w = exp2f(accs[mt][nt].w);
                        s_s[nt] += (pv.x + pv.y) + (pv.z + pv.w);
                        bf16x4 pk;
                        pk.x = (__bf16)pv.x; pk.y = (__bf16)pv.y;
                        pk.z = (__bf16)pv.z; pk.w = (__bf16)pv.w;
                        *(bf16x4*)(Psw + (nt * 16 + l16) * 72 + mt * 16 + quad * 4) = pk;
                    }
            }
            // ---- PV half A: V keys [0,64) (kk 0..1), P slot cols 0..63 ----
            {
                bf16x8 vf[2][4], pf[2][2];
#pragma unroll
                for (int kk = 0; kk < 2; kk++)
#pragma unroll
                    for (int nv = 0; nv < 4; nv++)
                        vf[kk][nv] = *(const bf16x8*)(Vtg + vtbase +
                                      (size_t)(nv * 16 + l16) * 128 +
                                      kk * 32 + quad * 8);
#pragma unroll
                for (int kk = 0; kk < 2; kk++)
#pragma unroll
                    for (int mtP = 0; mtP < 2; mtP++)
                        pf[kk][mtP] = *(const bf16x8*)(Psw + (mtP * 16 + l16) * 72 +
                                                       kk * 32 + quad * 8);
#pragma unroll
                for (int kk = 0; kk < 2; kk++)
#pragma unroll
                    for (int mtP = 0; mtP < 2; mtP++)
#pragma unroll
                        for (int nv = 0; nv < 4; nv++)
                            acc_o[mtP][nv] = MFMA16(pf[kk][mtP], vf[kk][nv],
                                                    acc_o[mtP][nv]);
            }

            // ======== HALF B: keys key0+[64,128), skipped if fully masked ========
            if (!skipB) {
                {
                    bf16x8 kf[2][4];
#pragma unroll
                    for (int kk = 0; kk < 2; kk++)
#pragma unroll
                        for (int mt = 0; mt < 4; mt++)
                            kf[kk][mt] = *(const bf16x8*)(Kg + hbase +
                                          (size_t)(key0 + 64 + mt * 16 + l16) * 64 +
                                          kk * 32 + quad * 8);
                    f32x4 accs[4][2];
#pragma unroll
                    for (int mt = 0; mt < 4; mt++) { accs[mt][0] = zz; accs[mt][1] = zz; }
#pragma unroll
                    for (int kk = 0; kk < 2; kk++)
#pragma unroll
                        for (int mt = 0; mt < 4; mt++) {
                            accs[mt][0] = MFMA16(kf[kk][mt], qf[0][kk], accs[mt][0]);
                            accs[mt][1] = MFMA16(kf[kk][mt], qf[1][kk], accs[mt][1]);
                        }
                    if (diag) {
#pragma unroll
                        for (int mt = 0; mt < 4; mt++)
#pragma unroll
                            for (int nt = 0; nt < 2; nt++) {
                                int q_g = q0 + nt * 16 + l16;
#pragma unroll
                                for (int r4 = 0; r4 < 4; r4++) {
                                    int key_g = key0 + 64 + mt * 16 + quad * 4 + r4;
                                    if (key_g > q_g) accs[mt][nt][r4] = -1e30f;
                                }
                            }
                    }
#pragma unroll
                    for (int mt = 0; mt < 4; mt++)
#pragma unroll
                        for (int nt = 0; nt < 2; nt++) {
                            f32x4 pv;
                            pv.x = exp2f(accs[mt][nt].x);
                            pv.y = exp2f(accs[mt][nt].y);
                            pv.z = exp2f(accs[mt][nt].z);
                            pv.w = exp2f(accs[mt][nt].w);
                            s_s[nt] += (pv.x + pv.y) + (pv.z + pv.w);
                            bf16x4 pk;
                            pk.x = (__bf16)pv.x; pk.y = (__bf16)pv.y;
                            pk.z = (__bf16)pv.z; pk.w = (__bf16)pv.w;
                            // same slot (cols 0..63): same-wave DS ops are
                            // in-order, PV-A reads completed first
                            *(bf16x4*)(Psw + (nt * 16 + l16) * 72 +
                                       mt * 16 + quad * 4) = pk;
                        }
                }
                // ---- PV half B: V keys [64,128) (kk 2..3), P slot cols 0..63 ----
                {
                    bf16x8 vf[2][4], pf[2][2];
#pragma unroll
                    for (int kk = 0; kk < 2; kk++)
#pragma unroll
                        for (int nv = 0; nv < 4; nv++)
                            vf[kk][nv] = *(const bf16x8*)(Vtg + vtbase +
                                          (size_t)(nv * 16 + l16) * 128 +
                                          (kk + 2) * 32 + quad * 8);
#pragma unroll
                    for (int kk = 0; kk < 2; kk++)
#pragma unroll
                        for (int mtP = 0; mtP < 2; mtP++)
                            pf[kk][mtP] = *(const bf16x8*)(Psw + (mtP * 16 + l16) * 72 +
                                                           kk * 32 + quad * 8);
#pragma unroll
                    for (int kk = 0; kk < 2; kk++)
#pragma unroll
                        for (int mtP = 0; mtP < 2; mtP++)
#pragma unroll
                            for (int nv = 0; nv < 4; nv++)
                                acc_o[mtP][nv] = MFMA16(pf[kk][mtP], vf[kk][nv],
                                                        acc_o[mtP][nv]);
                }
            }

#pragma unroll
            for (int nt = 0; nt < 2; nt++) {
                float t = s_s[nt];
                t += __shfl_xor(t, 16);
                t += __shfl_xor(t, 32);
                l_s[nt] += t;
            }
        }

        // ================= merge of 4 key-split partials (sum only) =============
        if (quad == 0) { Lw[wid][l16] = l_s[0]; Lw[wid][16 + l16] = l_s[1]; }
        __syncthreads();
        if (wid == 0 && quad == 0) {
#pragma unroll
            for (int nt = 0; nt < 2; nt++) {
                int qq = nt * 16 + l16;
                Linv[qq] = 1.0f / (Lw[0][qq] + Lw[1][qq] + Lw[2][qq] + Lw[3][qq]);
            }
        }
        // own-wave slot reused as f32 partial: Om[32 rows][72 stride]
        float* Omw = (float*)(smem + wid * 9216);
#pragma unroll
        for (int mtP = 0; mtP < 2; mtP++)
#pragma unroll
            for (int nv = 0; nv < 4; nv++)
#pragma unroll
                for (int r4 = 0; r4 < 4; r4++)
                    Omw[(mtP * 16 + quad * 4 + r4) * 72 + nv * 16 + l16] =
                        acc_o[mtP][nv][r4];
        __syncthreads();

        // sum 4 partials, scale by 1/l, write Y (16B coalesced)
        {
            const int q  = tid >> 3;          // 0..31
            const int c0 = (tid & 7) * 8;     // 0..56
            const float* Om = (const float*)smem;
            f32x4 s0 = zz, s1 = zz;
#pragma unroll
            for (int w = 0; w < 4; w++) {
                s0 += *(const f32x4*)(&Om[w * 2304 + q * 72 + c0]);
                s1 += *(const f32x4*)(&Om[w * 2304 + q * 72 + c0 + 4]);
            }
            float li = Linv[q];
            bf16x8 o;
            o[0] = (__bf16)(s0.x * li); o[1] = (__bf16)(s0.y * li);
            o[2] = (__bf16)(s0.z * li); o[3] = (__bf16)(s0.w * li);
            o[4] = (__bf16)(s1.x * li); o[5] = (__bf16)(s1.y * li);
            o[6] = (__bf16)(s1.z * li); o[7] = (__bf16)(s1.w * li);
            const int b = bh >> 4, h = bh & 15;
            *(bf16x8*)(Y + ((size_t)(b * 2048 + q0 + q)) * 1024 + h * 64 + c0) = o;
        }
        __syncthreads();   // protect smem/Lw reuse by the next item
    }
}

// ws layout (bf16 elems), 40 MB total:
// [0,4Mi)     x as bf16 (dead after qkv) -> reused as Y [B,T,C]
// [4Mi,8Mi)   W^T x4 (Wq,Wk,Wv,Wp)
// [8Mi,12Mi)  Q [B,H,T,HD] (pre-scaled)
// [12Mi,16Mi) K [B,H,T,HD]
// [16Mi,20Mi) V^T tiled [BH][16][64][128]  (written directly by qkv_gemm z=2)
#define XB_OFF  0
#define WT_OFF  4194304
#define Q_OFF   8388608
#define K_OFF   12582912
#define VT_OFF  16777216
#define Y_OFF   0

extern "C" void kernel_launch(void* const* d_in, const int* in_sizes, int n_in,
                              void* d_out, int out_size, void* d_ws, size_t ws_size,
                              hipStream_t stream) {
    const float* x  = (const float*)d_in[0];
    const float* Wq = (const float*)d_in[1];
    const float* bq = (const float*)d_in[2];
    const float* Wk = (const float*)d_in[3];
    const float* bk = (const float*)d_in[4];
    const float* Wv = (const float*)d_in[5];
    const float* bv = (const float*)d_in[6];
    const float* Wp = (const float*)d_in[7];
    const float* bp = (const float*)d_in[8];
    __bf16* ws  = (__bf16*)d_ws;
    float*  out = (float*)d_out;
    if (ws_size < (size_t)41943040) return;  // need 40 MB scratch

    convert_bf16<<<4096, 256, 0, stream>>>(x, ws + XB_OFF);
    transpose_w<<<dim3(32, 32, 4), dim3(32, 32), 0, stream>>>(Wq, Wk, Wv, Wp, ws + WT_OFF);
    qkv_gemm<<<dim3(8, 32, 3), 256, 0, stream>>>(ws + XB_OFF, ws + WT_OFF, bq, bk, bv,
                                                 ws + Q_OFF, ws + VT_OFF);
    attn_kernel<<<dim3(1024), 256, 0, stream>>>(ws + Q_OFF, ws + K_OFF, ws + VT_OFF,
                                                ws + Y_OFF);
    proj_gemm<<<dim3(8, 32), 256, 0, stream>>>(ws + Y_OFF, ws + WT_OFF + 3 * 1048576, bp, out);
}

// Round 10
// 245.153 us; speedup vs baseline: 1.0356x; 1.0323x over previous
//
#include <hip/hip_runtime.h>
#include <hip/hip_bf16.h>
#include <stdint.h>

typedef __bf16 bf16x8 __attribute__((ext_vector_type(8)));
typedef __bf16 bf16x4 __attribute__((ext_vector_type(4)));
typedef float  f32x4  __attribute__((ext_vector_type(4)));

#define MFMA16(a, b, c) __builtin_amdgcn_mfma_f32_16x16x32_bf16(a, b, c, 0, 0, 0)

// raw hardware exp2 (v_exp_f32, ~1 ULP). exp2f() w/o -ffast-math goes through
// __ocml_exp2_f32 (multi-instruction precise path) — suspected source of the
// ~1400 VALU-inst/tile invariant across v2b..v7.
__device__ __forceinline__ float ex2(float x) {
#if __has_builtin(__builtin_amdgcn_exp2f)
    return __builtin_amdgcn_exp2f(x);
#else
    return exp2f(x);
#endif
}

// async 16B global->LDS (dest = wave-uniform base + lane*16)
__device__ __forceinline__ void ld16(void* lds, const void* g) {
    __builtin_amdgcn_global_load_lds(
        (const __attribute__((address_space(1))) void*)(uintptr_t)g,
        (__attribute__((address_space(3))) void*)(uint32_t)(uintptr_t)lds,
        16, 0, 0);
}

// ---------------- f32 -> bf16 convert (x) -------------------------------------
__global__ __launch_bounds__(256) void convert_bf16(const float* __restrict__ src,
                                                    __bf16* __restrict__ dst) {
    int i = (blockIdx.x * 256 + threadIdx.x) * 4;
    float4 v = *(const float4*)(src + i);
    dst[i]     = (__bf16)v.x;
    dst[i + 1] = (__bf16)v.y;
    dst[i + 2] = (__bf16)v.z;
    dst[i + 3] = (__bf16)v.w;
}

// ---------------- weight transpose + cast: Wt[n][k] = (bf16)W[k][n] -----------
__global__ __launch_bounds__(1024) void transpose_w(const float* __restrict__ W0,
                                                    const float* __restrict__ W1,
                                                    const float* __restrict__ W2,
                                                    const float* __restrict__ W3,
                                                    __bf16* __restrict__ dst) {
    __shared__ __bf16 t[32][33];
    const int z = blockIdx.z;
    const float* W = (z == 0) ? W0 : (z == 1) ? W1 : (z == 2) ? W2 : W3;
    __bf16* D = dst + (size_t)z * 1048576;
    const int tx = threadIdx.x, ty = threadIdx.y;
    t[ty][tx] = (__bf16)W[(size_t)(blockIdx.y * 32 + ty) * 1024 + blockIdx.x * 32 + tx];
    __syncthreads();
    D[(size_t)(blockIdx.x * 32 + ty) * 1024 + blockIdx.y * 32 + tx] = t[tx][ty];
}

// ---------------- shared GEMM mainloop: C[128x128] += A[128xK] * BT[128xK]^T ----
__device__ __forceinline__ void gemm_mainloop(const __bf16* __restrict__ A,
                                              const __bf16* __restrict__ BT,
                                              int K, __bf16* As, __bf16* Bs,
                                              f32x4 acc[4][4]) {
    const int tid  = threadIdx.x;
    const int lane = tid & 63;
    const int wid  = tid >> 6;
    const int quad = lane >> 4;
    const int l16  = lane & 15;
    const int wm   = wid >> 1;
    const int wn   = wid & 1;

    const int srow = wid * 16 + (lane >> 2);
    const int scol = (lane & 3) * 8;
    const int sdst = wid * 512 + lane * 8;

    for (int k0 = 0; k0 < K; k0 += 32) {
        ld16(As + sdst,        A  + (size_t)srow        * K + k0 + scol);
        ld16(As + 2048 + sdst, A  + (size_t)(srow + 64) * K + k0 + scol);
        ld16(Bs + sdst,        BT + (size_t)srow        * K + k0 + scol);
        ld16(Bs + 2048 + sdst, BT + (size_t)(srow + 64) * K + k0 + scol);
        __syncthreads();
        bf16x8 af[4], bf[4];
#pragma unroll
        for (int mt = 0; mt < 4; mt++)
            af[mt] = *(const bf16x8*)(As + (wm * 64 + mt * 16 + l16) * 32 + quad * 8);
#pragma unroll
        for (int nt = 0; nt < 4; nt++)
            bf[nt] = *(const bf16x8*)(Bs + (wn * 64 + nt * 16 + l16) * 32 + quad * 8);
#pragma unroll
        for (int mt = 0; mt < 4; mt++)
#pragma unroll
            for (int nt = 0; nt < 4; nt++)
                acc[mt][nt] = MFMA16(af[mt], bf[nt], acc[mt][nt]);
        __syncthreads();
    }
}

// ---------------- 64-row GEMM mainloop: C[64x128] += A[64xK] * BT[128xK]^T ------
// 4 waves tile 2x2 over (64,128); wave tile 32x64 -> acc[2][4].
__device__ __forceinline__ void gemm_mainloop64(const __bf16* __restrict__ A,
                                                const __bf16* __restrict__ BT,
                                                int K, __bf16* As, __bf16* Bs,
                                                f32x4 acc[2][4]) {
    const int tid  = threadIdx.x;
    const int lane = tid & 63;
    const int wid  = tid >> 6;
    const int quad = lane >> 4;
    const int l16  = lane & 15;
    const int wm   = wid >> 1;
    const int wn   = wid & 1;

    const int srow = wid * 16 + (lane >> 2);   // 0..63
    const int scol = (lane & 3) * 8;
    const int sdst = wid * 512 + lane * 8;

    for (int k0 = 0; k0 < K; k0 += 32) {
        ld16(As + sdst,        A  + (size_t)srow        * K + k0 + scol);
        ld16(Bs + sdst,        BT + (size_t)srow        * K + k0 + scol);
        ld16(Bs + 2048 + sdst, BT + (size_t)(srow + 64) * K + k0 + scol);
        __syncthreads();
        bf16x8 af[2], bf[4];
#pragma unroll
        for (int mt = 0; mt < 2; mt++)
            af[mt] = *(const bf16x8*)(As + (wm * 32 + mt * 16 + l16) * 32 + quad * 8);
#pragma unroll
        for (int nt = 0; nt < 4; nt++)
            bf[nt] = *(const bf16x8*)(Bs + (wn * 64 + nt * 16 + l16) * 32 + quad * 8);
#pragma unroll
        for (int mt = 0; mt < 2; mt++)
#pragma unroll
            for (int nt = 0; nt < 4; nt++)
                acc[mt][nt] = MFMA16(af[mt], bf[nt], acc[mt][nt]);
        __syncthreads();
    }
}

// ---------------- QKV projection: X @ W{q,k,v} + b ------------------------------
// z=0 -> Q [B,H,T,HD] PRE-SCALED by (1/8)*log2(e), z=1 -> K [B,H,T,HD],
// z=2 -> V^T TILED: [BH][T/128][HD=64][128]
__global__ __launch_bounds__(256) void qkv_gemm(const __bf16* __restrict__ X,
                                                const __bf16* __restrict__ WTb,
                                                const float* __restrict__ b0,
                                                const float* __restrict__ b1,
                                                const float* __restrict__ b2,
                                                __bf16* __restrict__ qk,
                                                __bf16* __restrict__ vt) {
    __shared__ __attribute__((aligned(16))) __bf16 As[4096];
    __shared__ __attribute__((aligned(16))) __bf16 Bs[4096];
    const int z = blockIdx.z;
    const __bf16* BT   = WTb + (size_t)z * 1048576;
    const float* bias  = (z == 0) ? b0 : (z == 1) ? b1 : b2;
    const int m0 = blockIdx.y * 128, n0 = blockIdx.x * 128;
    f32x4 acc[4][4];
    const f32x4 zz = {0.f, 0.f, 0.f, 0.f};
#pragma unroll
    for (int i = 0; i < 4; i++)
#pragma unroll
        for (int j = 0; j < 4; j++) acc[i][j] = zz;
    gemm_mainloop(X + (size_t)m0 * 1024, BT + (size_t)n0 * 1024, 1024, As, Bs, acc);

    const int lane = threadIdx.x & 63, wid = threadIdx.x >> 6;
    const int quad = lane >> 4, l16 = lane & 15, wm = wid >> 1, wn = wid & 1;
    if (z == 2) {
#pragma unroll
        for (int nt = 0; nt < 4; nt++) {
            int col = n0 + wn * 64 + nt * 16 + l16;
            float bv = bias[col];
            int h = col >> 6, hd = col & 63;
#pragma unroll
            for (int mt = 0; mt < 4; mt++) {
                int m = m0 + wm * 64 + mt * 16 + quad * 4;
                int b = m >> 11, tt = m & 2047;
                int ttile = tt >> 7, toff = tt & 127;
                bf16x4 pk;
                pk.x = (__bf16)(acc[mt][nt].x + bv);
                pk.y = (__bf16)(acc[mt][nt].y + bv);
                pk.z = (__bf16)(acc[mt][nt].z + bv);
                pk.w = (__bf16)(acc[mt][nt].w + bv);
                *(bf16x4*)(vt + (((size_t)(b * 16 + h) * 16 + ttile) * 64 + hd) * 128 +
                           toff) = pk;
            }
        }
    } else {
        // softmax scale (1/sqrt(64))*log2(e) folded into Q here (z==0)
        const float sq = (z == 0) ? 0.18033688011112042f : 1.0f;
        __bf16* dst = qk + (size_t)z * 4194304;
#pragma unroll
        for (int nt = 0; nt < 4; nt++) {
            int col = n0 + wn * 64 + nt * 16 + l16;
            float bv = bias[col];
            int h = col >> 6, hd = col & 63;
#pragma unroll
            for (int mt = 0; mt < 4; mt++) {
#pragma unroll
                for (int r4 = 0; r4 < 4; r4++) {
                    int m = m0 + wm * 64 + mt * 16 + quad * 4 + r4;
                    int b = m >> 11, tt = m & 2047;
                    float v = (acc[mt][nt][r4] + bv) * sq;
                    dst[((size_t)((b * 16 + h) * 2048 + tt)) * 64 + hd] = (__bf16)v;
                }
            }
        }
    }
}

// ---------------- output projection: Y @ Wp + bp -> out [B,T,C] f32 ------------
// 64x128 tiles -> 512 blocks (2/CU; 128x128 gave only 256 = 1/CU starvation)
__global__ __launch_bounds__(256) void proj_gemm(const __bf16* __restrict__ Yw,
                                                 const __bf16* __restrict__ WT,
                                                 const float* __restrict__ bias,
                                                 float* __restrict__ out) {
    __shared__ __attribute__((aligned(16))) __bf16 As[2048];
    __shared__ __attribute__((aligned(16))) __bf16 Bs[4096];
    const int m0 = blockIdx.y * 64, n0 = blockIdx.x * 128;
    f32x4 acc[2][4];
    const f32x4 zz = {0.f, 0.f, 0.f, 0.f};
#pragma unroll
    for (int i = 0; i < 2; i++)
#pragma unroll
        for (int j = 0; j < 4; j++) acc[i][j] = zz;
    gemm_mainloop64(Yw + (size_t)m0 * 1024, WT + (size_t)n0 * 1024, 1024, As, Bs, acc);

    const int lane = threadIdx.x & 63, wid = threadIdx.x >> 6;
    const int quad = lane >> 4, l16 = lane & 15, wm = wid >> 1, wn = wid & 1;
#pragma unroll
    for (int nt = 0; nt < 4; nt++) {
        int col = n0 + wn * 64 + nt * 16 + l16;
        float bv = bias[col];
#pragma unroll
        for (int mt = 0; mt < 2; mt++) {
#pragma unroll
            for (int r4 = 0; r4 < 4; r4++) {
                int m = m0 + wm * 32 + mt * 16 + quad * 4 + r4;
                out[(size_t)m * 1024 + col] = acc[mt][nt][r4] + bv;
            }
        }
    }
}

// ---------------- flash attention v8 -------------------------------------------
// Identical to v7 except exp2f -> __builtin_amdgcn_exp2f (single v_exp_f32).
__global__ __launch_bounds__(256, 2) void attn_kernel(const __bf16* __restrict__ Qg,
                                                      const __bf16* __restrict__ Kg,
                                                      const __bf16* __restrict__ Vtg,
                                                      __bf16* __restrict__ Y) {
    __shared__ __attribute__((aligned(16))) unsigned char smem[4 * 9216];
    __shared__ __attribute__((aligned(16))) float Lw[4][32];   // per-wave l
    __shared__ __attribute__((aligned(16))) float Linv[32];    // 1/l merged

    const int tid  = threadIdx.x;
    const int lane = tid & 63;
    const int wid  = tid >> 6;
    const int quad = lane >> 4;
    const int l16  = lane & 15;
    const int p    = blockIdx.x;
    const int bh      = (p & 7) * 4 + ((p >> 3) & 3);  // XCD-pinned head
    const int pairidx = p >> 5;                        // 0..31
    const f32x4 zz = {0.f, 0.f, 0.f, 0.f};

    __bf16* Psw = (__bf16*)(smem + wid * 9216);

#pragma unroll 1
    for (int itm = 0; itm < 2; itm++) {
        const int bx  = itm ? (63 - pairidx) : pairidx;
        const int q0  = bx * 32;
        const int ktlast = bx >> 2;
        const bool halfdiag = (bx & 3) < 2;   // diag tile: keys 64-127 all masked
        const size_t hbase = (size_t)bh * (2048 * 64);

        // Q fragments (B-layout, pre-scaled) for the item's 32 q rows
        bf16x8 qf[2][2];
#pragma unroll
        for (int nt = 0; nt < 2; nt++)
#pragma unroll
            for (int kk = 0; kk < 2; kk++)
                qf[nt][kk] = *(const bf16x8*)(Qg + hbase +
                                              (size_t)(q0 + nt * 16 + l16) * 64 +
                                              kk * 32 + quad * 8);

        f32x4 acc_o[2][4];
#pragma unroll
        for (int i = 0; i < 2; i++)
#pragma unroll
            for (int j = 0; j < 4; j++) acc_o[i][j] = zz;
        float l_s[2] = {0.f, 0.f};

        for (int kt = wid; kt <= ktlast; kt += 4) {
            const int key0 = kt << 7;
            const bool diag = (kt == ktlast);
            const bool skipB = diag && halfdiag;
            const size_t vtbase = ((size_t)bh * 16 + kt) * 8192;  // tiled V^T
            float s_s[2] = {0.f, 0.f};

            // ======== HALF A: keys key0+[0,64) ========
            {
                bf16x8 kf[2][4];
#pragma unroll
                for (int kk = 0; kk < 2; kk++)
#pragma unroll
                    for (int mt = 0; mt < 4; mt++)
                        kf[kk][mt] = *(const bf16x8*)(Kg + hbase +
                                      (size_t)(key0 + mt * 16 + l16) * 64 +
                                      kk * 32 + quad * 8);
                f32x4 accs[4][2];
#pragma unroll
                for (int mt = 0; mt < 4; mt++) { accs[mt][0] = zz; accs[mt][1] = zz; }
#pragma unroll
                for (int kk = 0; kk < 2; kk++)
#pragma unroll
                    for (int mt = 0; mt < 4; mt++) {
                        accs[mt][0] = MFMA16(kf[kk][mt], qf[0][kk], accs[mt][0]);
                        accs[mt][1] = MFMA16(kf[kk][mt], qf[1][kk], accs[mt][1]);
                    }
                if (diag) {
#pragma unroll
                    for (int mt = 0; mt < 4; mt++)
#pragma unroll
                        for (int nt = 0; nt < 2; nt++) {
                            int q_g = q0 + nt * 16 + l16;
#pragma unroll
                            for (int r4 = 0; r4 < 4; r4++) {
                                int key_g = key0 + mt * 16 + quad * 4 + r4;
                                if (key_g > q_g) accs[mt][nt][r4] = -1e30f;
                            }
                        }
                }
#pragma unroll
                for (int mt = 0; mt < 4; mt++)
#pragma unroll
                    for (int nt = 0; nt < 2; nt++) {
                        f32x4 pv;
                        pv.x = ex2(accs[mt][nt].x);
                        pv.y = ex2(accs[mt][nt].y);
                        pv.z = ex2(accs[mt][nt].z);
                        pv.w = ex2(accs[mt][nt].w);
                        s_s[nt] += (pv.x + pv.y) + (pv.z + pv.w);
                        bf16x4 pk;
                        pk.x = (__bf16)pv.x; pk.y = (__bf16)pv.y;
                        pk.z = (__bf16)pv.z; pk.w = (__bf16)pv.w;
                        *(bf16x4*)(Psw + (nt * 16 + l16) * 72 + mt * 16 + quad * 4) = pk;
                    }
            }
            // ---- PV half A: V keys [0,64) (kk 0..1), P slot cols 0..63 ----
            {
                bf16x8 vf[2][4], pf[2][2];
#pragma unroll
                for (int kk = 0; kk < 2; kk++)
#pragma unroll
                    for (int nv = 0; nv < 4; nv++)
                        vf[kk][nv] = *(const bf16x8*)(Vtg + vtbase +
                                      (size_t)(nv * 16 + l16) * 128 +
                                      kk * 32 + quad * 8);
#pragma unroll
                for (int kk = 0; kk < 2; kk++)
#pragma unroll
                    for (int mtP = 0; mtP < 2; mtP++)
                        pf[kk][mtP] = *(const bf16x8*)(Psw + (mtP * 16 + l16) * 72 +
                                                       kk * 32 + quad * 8);
#pragma unroll
                for (int kk = 0; kk < 2; kk++)
#pragma unroll
                    for (int mtP = 0; mtP < 2; mtP++)
#pragma unroll
                        for (int nv = 0; nv < 4; nv++)
                            acc_o[mtP][nv] = MFMA16(pf[kk][mtP], vf[kk][nv],
                                                    acc_o[mtP][nv]);
            }

            // ======== HALF B: keys key0+[64,128), skipped if fully masked ========
            if (!skipB) {
                {
                    bf16x8 kf[2][4];
#pragma unroll
                    for (int kk = 0; kk < 2; kk++)
#pragma unroll
                        for (int mt = 0; mt < 4; mt++)
                            kf[kk][mt] = *(const bf16x8*)(Kg + hbase +
                                          (size_t)(key0 + 64 + mt * 16 + l16) * 64 +
                                          kk * 32 + quad * 8);
                    f32x4 accs[4][2];
#pragma unroll
                    for (int mt = 0; mt < 4; mt++) { accs[mt][0] = zz; accs[mt][1] = zz; }
#pragma unroll
                    for (int kk = 0; kk < 2; kk++)
#pragma unroll
                        for (int mt = 0; mt < 4; mt++) {
                            accs[mt][0] = MFMA16(kf[kk][mt], qf[0][kk], accs[mt][0]);
                            accs[mt][1] = MFMA16(kf[kk][mt], qf[1][kk], accs[mt][1]);
                        }
                    if (diag) {
#pragma unroll
                        for (int mt = 0; mt < 4; mt++)
#pragma unroll
                            for (int nt = 0; nt < 2; nt++) {
                                int q_g = q0 + nt * 16 + l16;
#pragma unroll
                                for (int r4 = 0; r4 < 4; r4++) {
                                    int key_g = key0 + 64 + mt * 16 + quad * 4 + r4;
                                    if (key_g > q_g) accs[mt][nt][r4] = -1e30f;
                                }
                            }
                    }
#pragma unroll
                    for (int mt = 0; mt < 4; mt++)
#pragma unroll
                        for (int nt = 0; nt < 2; nt++) {
                            f32x4 pv;
                            pv.x = ex2(accs[mt][nt].x);
                            pv.y = ex2(accs[mt][nt].y);
                            pv.z = ex2(accs[mt][nt].z);
                            pv.w = ex2(accs[mt][nt].w);
                            s_s[nt] += (pv.x + pv.y) + (pv.z + pv.w);
                            bf16x4 pk;
                            pk.x = (__bf16)pv.x; pk.y = (__bf16)pv.y;
                            pk.z = (__bf16)pv.z; pk.w = (__bf16)pv.w;
                            *(bf16x4*)(Psw + (nt * 16 + l16) * 72 +
                                       mt * 16 + quad * 4) = pk;
                        }
                }
                // ---- PV half B: V keys [64,128) (kk 2..3), P slot cols 0..63 ----
                {
                    bf16x8 vf[2][4], pf[2][2];
#pragma unroll
                    for (int kk = 0; kk < 2; kk++)
#pragma unroll
                        for (int nv = 0; nv < 4; nv++)
                            vf[kk][nv] = *(const bf16x8*)(Vtg + vtbase +
                                          (size_t)(nv * 16 + l16) * 128 +
                                          (kk + 2) * 32 + quad * 8);
#pragma unroll
                    for (int kk = 0; kk < 2; kk++)
#pragma unroll
                        for (int mtP = 0; mtP < 2; mtP++)
                            pf[kk][mtP] = *(const bf16x8*)(Psw + (mtP * 16 + l16) * 72 +
                                                           kk * 32 + quad * 8);
#pragma unroll
                    for (int kk = 0; kk < 2; kk++)
#pragma unroll
                        for (int mtP = 0; mtP < 2; mtP++)
#pragma unroll
                            for (int nv = 0; nv < 4; nv++)
                                acc_o[mtP][nv] = MFMA16(pf[kk][mtP], vf[kk][nv],
                                                        acc_o[mtP][nv]);
                }
            }

#pragma unroll
            for (int nt = 0; nt < 2; nt++) {
                float t = s_s[nt];
                t += __shfl_xor(t, 16);
                t += __shfl_xor(t, 32);
                l_s[nt] += t;
            }
        }

        // ================= merge of 4 key-split partials (sum only) =============
        if (quad == 0) { Lw[wid][l16] = l_s[0]; Lw[wid][16 + l16] = l_s[1]; }
        __syncthreads();
        if (wid == 0 && quad == 0) {
#pragma unroll
            for (int nt = 0; nt < 2; nt++) {
                int qq = nt * 16 + l16;
                Linv[qq] = 1.0f / (Lw[0][qq] + Lw[1][qq] + Lw[2][qq] + Lw[3][qq]);
            }
        }
        // own-wave slot reused as f32 partial: Om[32 rows][72 stride]
        float* Omw = (float*)(smem + wid * 9216);
#pragma unroll
        for (int mtP = 0; mtP < 2; mtP++)
#pragma unroll
            for (int nv = 0; nv < 4; nv++)
#pragma unroll
                for (int r4 = 0; r4 < 4; r4++)
                    Omw[(mtP * 16 + quad * 4 + r4) * 72 + nv * 16 + l16] =
                        acc_o[mtP][nv][r4];
        __syncthreads();

        // sum 4 partials, scale by 1/l, write Y (16B coalesced)
        {
            const int q  = tid >> 3;          // 0..31
            const int c0 = (tid & 7) * 8;     // 0..56
            const float* Om = (const float*)smem;
            f32x4 s0 = zz, s1 = zz;
#pragma unroll
            for (int w = 0; w < 4; w++) {
                s0 += *(const f32x4*)(&Om[w * 2304 + q * 72 + c0]);
                s1 += *(const f32x4*)(&Om[w * 2304 + q * 72 + c0 + 4]);
            }
            float li = Linv[q];
            bf16x8 o;
            o[0] = (__bf16)(s0.x * li); o[1] = (__bf16)(s0.y * li);
            o[2] = (__bf16)(s0.z * li); o[3] = (__bf16)(s0.w * li);
            o[4] = (__bf16)(s1.x * li); o[5] = (__bf16)(s1.y * li);
            o[6] = (__bf16)(s1.z * li); o[7] = (__bf16)(s1.w * li);
            const int b = bh >> 4, h = bh & 15;
            *(bf16x8*)(Y + ((size_t)(b * 2048 + q0 + q)) * 1024 + h * 64 + c0) = o;
        }
        __syncthreads();   // protect smem/Lw reuse by the next item
    }
}

// ws layout (bf16 elems), 40 MB total:
// [0,4Mi)     x as bf16 (dead after qkv) -> reused as Y [B,T,C]
// [4Mi,8Mi)   W^T x4 (Wq,Wk,Wv,Wp)
// [8Mi,12Mi)  Q [B,H,T,HD] (pre-scaled)
// [12Mi,16Mi) K [B,H,T,HD]
// [16Mi,20Mi) V^T tiled [BH][16][64][128]  (written directly by qkv_gemm z=2)
#define XB_OFF  0
#define WT_OFF  4194304
#define Q_OFF   8388608
#define K_OFF   12582912
#define VT_OFF  16777216
#define Y_OFF   0

extern "C" void kernel_launch(void* const* d_in, const int* in_sizes, int n_in,
                              void* d_out, int out_size, void* d_ws, size_t ws_size,
                              hipStream_t stream) {
    const float* x  = (const float*)d_in[0];
    const float* Wq = (const float*)d_in[1];
    const float* bq = (const float*)d_in[2];
    const float* Wk = (const float*)d_in[3];
    const float* bk = (const float*)d_in[4];
    const float* Wv = (const float*)d_in[5];
    const float* bv = (const float*)d_in[6];
    const float* Wp = (const float*)d_in[7];
    const float* bp = (const float*)d_in[8];
    __bf16* ws  = (__bf16*)d_ws;
    float*  out = (float*)d_out;
    if (ws_size < (size_t)41943040) return;  // need 40 MB scratch

    convert_bf16<<<4096, 256, 0, stream>>>(x, ws + XB_OFF);
    transpose_w<<<dim3(32, 32, 4), dim3(32, 32), 0, stream>>>(Wq, Wk, Wv, Wp, ws + WT_OFF);
    qkv_gemm<<<dim3(8, 32, 3), 256, 0, stream>>>(ws + XB_OFF, ws + WT_OFF, bq, bk, bv,
                                                 ws + Q_OFF, ws + VT_OFF);
    attn_kernel<<<dim3(1024), 256, 0, stream>>>(ws + Q_OFF, ws + K_OFF, ws + VT_OFF,
                                                ws + Y_OFF);
    proj_gemm<<<dim3(8, 64), 256, 0, stream>>>(ws + Y_OFF, ws + WT_OFF + 3 * 1048576, bp, out);
}